// Round 3
// baseline (819.920 us; speedup 1.0000x reference)
//
#include <hip/hip_runtime.h>
#include <hip/hip_bf16.h>
#include <hip/hip_cooperative_groups.h>
#include <math.h>

namespace cg = cooperative_groups;

// ---------------------------------------------------------------------------
// ThreeHeadedDecoder, fully fused single cooperative kernel (conservative
// occupancy). V=50257, E=512, H=1024, C=1024, L=1024, S=2048, NL=2. All fp32.
//
// Grid: 512 blocks x 256 threads, __launch_bounds__(256,2). At ~80-100 VGPR
// the runtime sees >=4 blocks/CU co-residency -> 512-block cooperative
// launch has >=2x margin (R2 failed at the exact 1024 = 4/CU boundary).
//
// ws layout (floats):
//   [0,1024)       h_0
//   [1024,5120)    concat_in = [h_1 | lctx_out | rctx_out | lemma_out]
//   [5120,8192)    v[3][1024]      (atomic accum, zeroed in P1)
//   [8192,14336)   e[3][2048]
//   [14336,15360)  concat_out
// d_out layout: logits[50257], h_new[2][1024], c_new[2][1024]
// ---------------------------------------------------------------------------

#define NV 50257
#define GRID 512

struct Params {
    const int* ids;
    const float *h0, *c0, *lctx, *rctx, *lemma, *emb;
    const float *W_ih0, *W_hh0, *b_ih0, *b_hh0;
    const float *W_ih1, *W_hh1, *b_ih1, *b_hh1;
    const float *W_left, *W_right, *W_lemma;
    const float *W_concat, *b_concat, *W_out, *b_out;
    float *out, *ws;
};

__device__ __forceinline__ float wave_sum(float v) {
#pragma unroll
    for (int o = 32; o > 0; o >>= 1) v += __shfl_down(v, o, 64);
    return v;
}

__device__ __forceinline__ float dot4(float4 a, float4 b) {
    return a.x * b.x + a.y * b.y + a.z * b.z + a.w * b.w;
}

__device__ __forceinline__ float sigmoidf_(float x) {
    return 1.0f / (1.0f + expf(-x));
}

__global__ __launch_bounds__(256, 2) void fused_decoder(Params p) {
    cg::grid_group grid = cg::this_grid();
    const int bid  = blockIdx.x;        // 0..511
    const int tid  = threadIdx.x;
    const int w    = tid >> 6;          // wave 0..3
    const int lane = tid & 63;

    float* h0_ws = p.ws;                // [1024]
    float* cin   = p.ws + 1024;         // [4096]: h_1 | ctx_out[3][1024]
    float* vbuf  = p.ws + 5120;         // [3][1024]
    float* ebuf  = p.ws + 8192;         // [3][2048]
    float* cout  = p.ws + 14336;        // [1024]
    float* h_out = p.out + NV;          // [2][1024]
    float* c_out = p.out + NV + 2048;   // [2][1024]

    __shared__ float g[4];
    __shared__ float red[256];

    // ================= P1: LSTM layer 0 (+ zero atomic accumulators) ======
    // zero ws[2048,8192) = ctx_out (3k) + v (3k); first used in P3/P5.
    if (bid < 24) {
        p.ws[2048 + bid * 256 + tid] = 0.0f;
    }
    {
        const float* x = p.emb + (size_t)512 * (size_t)p.ids[0];
        for (int k = bid; k < 1024; k += GRID) {
            const int row = w * 1024 + k;
            float acc = 0.0f;
            {
                const float4* r4 = (const float4*)(p.W_ih0 + (size_t)row * 512);
                const float4* x4 = (const float4*)x;
#pragma unroll
                for (int j = 0; j < 2; ++j) acc += dot4(r4[lane + 64 * j], x4[lane + 64 * j]);
            }
            {
                const float4* r4 = (const float4*)(p.W_hh0 + (size_t)row * 1024);
                const float4* h4 = (const float4*)p.h0;
#pragma unroll
                for (int j = 0; j < 4; ++j) acc += dot4(r4[lane + 64 * j], h4[lane + 64 * j]);
            }
            acc = wave_sum(acc);
            if (lane == 0) g[w] = acc + p.b_ih0[row] + p.b_hh0[row];
            __syncthreads();
            if (tid == 0) {
                float i_ = sigmoidf_(g[0]);
                float f_ = sigmoidf_(g[1]);
                float g_ = tanhf(g[2]);
                float o_ = sigmoidf_(g[3]);
                float c_new = f_ * p.c0[k] + i_ * g_;
                float h_new = o_ * tanhf(c_new);
                h0_ws[k]  = h_new;
                h_out[k]  = h_new;
                c_out[k]  = c_new;
            }
            __syncthreads();   // protect g before next iteration overwrites
        }
    }
    grid.sync();

    // ================= P2: LSTM layer 1 ====================================
    {
        for (int k = bid; k < 1024; k += GRID) {
            const int row = w * 1024 + k;
            float acc = 0.0f;
            {
                const float4* r4 = (const float4*)(p.W_ih1 + (size_t)row * 1024);
                const float4* x4 = (const float4*)h0_ws;
#pragma unroll
                for (int j = 0; j < 4; ++j) acc += dot4(r4[lane + 64 * j], x4[lane + 64 * j]);
            }
            {
                const float4* r4 = (const float4*)(p.W_hh1 + (size_t)row * 1024);
                const float4* h4 = (const float4*)(p.h0 + 1024);
#pragma unroll
                for (int j = 0; j < 4; ++j) acc += dot4(r4[lane + 64 * j], h4[lane + 64 * j]);
            }
            acc = wave_sum(acc);
            if (lane == 0) g[w] = acc + p.b_ih1[row] + p.b_hh1[row];
            __syncthreads();
            if (tid == 0) {
                float i_ = sigmoidf_(g[0]);
                float f_ = sigmoidf_(g[1]);
                float g_ = tanhf(g[2]);
                float o_ = sigmoidf_(g[3]);
                float c_new = f_ * p.c0[1024 + k] + i_ * g_;
                float h_new = o_ * tanhf(c_new);
                cin[k]          = h_new;   // rnn_output = head of concat_in
                h_out[1024 + k] = h_new;
                c_out[1024 + k] = c_new;
            }
            __syncthreads();
        }
    }
    grid.sync();

    // ================= P3: v_a = q @ W_a  (b.q dropped: softmax-invariant) =
    if (bid < 192) {
        const int a = bid >> 6;
        const int chunk = bid & 63;
        const float* W = (a == 0) ? p.W_left : (a == 1) ? p.W_right : p.W_lemma;
        const int c = tid * 4;
        float4 acc = make_float4(0.f, 0.f, 0.f, 0.f);
#pragma unroll 4
        for (int h = chunk * 16; h < chunk * 16 + 16; ++h) {
            float qh = cin[h];
            float4 wv = *(const float4*)(W + (size_t)h * 1024 + c);
            acc.x += wv.x * qh; acc.y += wv.y * qh;
            acc.z += wv.z * qh; acc.w += wv.w * qh;
        }
        float* vd = vbuf + a * 1024 + c;
        atomicAdd(vd + 0, acc.x); atomicAdd(vd + 1, acc.y);
        atomicAdd(vd + 2, acc.z); atomicAdd(vd + 3, acc.w);
    }
    grid.sync();

    // ================= P4: e[a][s] = ctx_a[s] . v_a  (6144 wave-dots) ======
    {
        const int wid = bid * 4 + w;   // 0..2047
        for (int rr = wid; rr < 6144; rr += GRID * 4) {
            const int a = rr >> 11;
            const int s = rr & 2047;
            const float* ctx = (a == 0) ? p.lctx : (a == 1) ? p.rctx : p.lemma;
            const float4* r4 = (const float4*)(ctx + (size_t)s * 1024);
            const float4* v4 = (const float4*)(vbuf + a * 1024);
            float acc = 0.0f;
#pragma unroll
            for (int j = 0; j < 4; ++j) acc += dot4(r4[lane + 64 * j], v4[lane + 64 * j]);
            acc = wave_sum(acc);
            if (lane == 0) ebuf[rr] = acc;
        }
    }
    grid.sync();

    // ================= P5: softmax + weighted context sum ==================
    if (bid < 192) {
        const int a = bid >> 6;
        const int chunk = bid & 63;
        const float* ctx = (a == 0) ? p.lctx : (a == 1) ? p.rctx : p.lemma;
        const float* ea = ebuf + a * 2048;

        float m = -1e30f;
        for (int i = tid; i < 2048; i += 256) m = fmaxf(m, ea[i]);
        red[tid] = m; __syncthreads();
        for (int o = 128; o > 0; o >>= 1) {
            if (tid < o) red[tid] = fmaxf(red[tid], red[tid + o]);
            __syncthreads();
        }
        m = red[0]; __syncthreads();

        float ssum = 0.0f;
        for (int i = tid; i < 2048; i += 256) ssum += expf(ea[i] - m);
        red[tid] = ssum; __syncthreads();
        for (int o = 128; o > 0; o >>= 1) {
            if (tid < o) red[tid] += red[tid + o];
            __syncthreads();
        }
        const float inv = 1.0f / red[0];

        const int c = tid * 4;
        float4 acc = make_float4(0.f, 0.f, 0.f, 0.f);
        for (int s = chunk * 32; s < chunk * 32 + 32; ++s) {
            float wgt = expf(ea[s] - m) * inv;
            float4 cv = *(const float4*)(ctx + (size_t)s * 1024 + c);
            acc.x += wgt * cv.x; acc.y += wgt * cv.y;
            acc.z += wgt * cv.z; acc.w += wgt * cv.w;
        }
        float* od = cin + 1024 + a * 1024 + c;   // ctx_out region of concat_in
        atomicAdd(od + 0, acc.x); atomicAdd(od + 1, acc.y);
        atomicAdd(od + 2, acc.z); atomicAdd(od + 3, acc.w);
    }
    grid.sync();

    // ================= P6: concat_out = tanh(W_concat . concat_in + b) =====
    if (bid < 256) {
        const int j = bid * 4 + w;
        const float4* r4 = (const float4*)(p.W_concat + (size_t)j * 4096);
        const float4* x4 = (const float4*)cin;
        float acc = 0.0f;
#pragma unroll 4
        for (int i = lane; i < 1024; i += 64) acc += dot4(r4[i], x4[i]);
        acc = wave_sum(acc);
        if (lane == 0) cout[j] = tanhf(acc + p.b_concat[j]);
    }
    grid.sync();

    // ================= P7: logits = W_out . concat_out + b_out =============
    {
        const int wid = bid * 4 + w;        // 0..2047
        const int stride = GRID * 4;        // 2048
        const float4* x4 = (const float4*)cout;
        // hoist the invariant x fragment (16 floats/lane) into registers
        const float4 xr0 = x4[lane];
        const float4 xr1 = x4[lane + 64];
        const float4 xr2 = x4[lane + 128];
        const float4 xr3 = x4[lane + 192];
        for (int vr0 = wid; vr0 < NV; vr0 += 2 * stride) {
            const int vr1 = vr0 + stride;
            const float4* r0 = (const float4*)(p.W_out + (size_t)vr0 * 1024);
            float acc0 = dot4(r0[lane], xr0) + dot4(r0[lane + 64], xr1)
                       + dot4(r0[lane + 128], xr2) + dot4(r0[lane + 192], xr3);
            float acc1 = 0.0f;
            if (vr1 < NV) {
                const float4* r1 = (const float4*)(p.W_out + (size_t)vr1 * 1024);
                acc1 = dot4(r1[lane], xr0) + dot4(r1[lane + 64], xr1)
                     + dot4(r1[lane + 128], xr2) + dot4(r1[lane + 192], xr3);
            }
            acc0 = wave_sum(acc0);
            acc1 = wave_sum(acc1);
            if (lane == 0) {
                p.out[vr0] = acc0 + p.b_out[vr0];
                if (vr1 < NV) p.out[vr1] = acc1 + p.b_out[vr1];
            }
        }
    }
}

extern "C" void kernel_launch(void* const* d_in, const int* in_sizes, int n_in,
                              void* d_out, int out_size, void* d_ws, size_t ws_size,
                              hipStream_t stream) {
    Params p;
    p.ids      = (const int*)  d_in[0];
    p.h0       = (const float*)d_in[1];
    p.c0       = (const float*)d_in[2];
    p.lctx     = (const float*)d_in[3];
    p.rctx     = (const float*)d_in[4];
    p.lemma    = (const float*)d_in[5];
    p.emb      = (const float*)d_in[6];
    p.W_ih0    = (const float*)d_in[7];
    p.W_hh0    = (const float*)d_in[8];
    p.b_ih0    = (const float*)d_in[9];
    p.b_hh0    = (const float*)d_in[10];
    p.W_ih1    = (const float*)d_in[11];
    p.W_hh1    = (const float*)d_in[12];
    p.b_ih1    = (const float*)d_in[13];
    p.b_hh1    = (const float*)d_in[14];
    p.W_left   = (const float*)d_in[15];
    // d_in[16] b_left, d_in[18] b_right, d_in[20] b_lemma: softmax-invariant, dropped
    p.W_right  = (const float*)d_in[17];
    p.W_lemma  = (const float*)d_in[19];
    p.W_concat = (const float*)d_in[21];
    p.b_concat = (const float*)d_in[22];
    p.W_out    = (const float*)d_in[23];
    p.b_out    = (const float*)d_in[24];
    p.out      = (float*)d_out;
    p.ws       = (float*)d_ws;
    (void)in_sizes; (void)n_in; (void)out_size; (void)ws_size;

    void* args[] = { &p };
    hipLaunchCooperativeKernel((void*)fused_decoder, dim3(GRID), dim3(256),
                               args, 0, stream);
}

// Round 4
// 456.219 us; speedup vs baseline: 1.7972x; 1.7972x over previous
//
#include <hip/hip_runtime.h>
#include <hip/hip_bf16.h>
#include <math.h>

// ---------------------------------------------------------------------------
// ThreeHeadedDecoder: batch-1 LSTM decoder step, all fp32 matvecs (HBM-bound).
// V=50257, E=512, H=1024, C=1024, L=1024, S=2048, NL=2
// Multi-kernel stream structure (R1, proven): cooperative grid.sync is 8x
// slower on this ROCm (fabric-saturating spin), harness fixed overhead in the
// timed window is ~366 us, our device time target is ~70-85 us.
//
// ws layout (floats):
//   [0,1024)      h_0
//   [1024,2048)   h_1            (head of concat_in)
//   [2048,5120)   ctx_out[3][1024] (rest of concat_in; atomic accum)
//   [5120,8192)   v[3][1024]       (atomic accum)
//   [8192,14336)  e[3][2048]
//   [20480,21504) concat_out[1024]
// d_out layout: logits[50257], h_new[2][1024], c_new[2][1024]
// ---------------------------------------------------------------------------

#define WS_H0        0
#define WS_CONCAT_IN 1024
#define WS_CTXOUT    2048
#define WS_V         5120
#define WS_E         8192
#define WS_COUT      20480
#define OUT_V        50257

__device__ __forceinline__ float wave_sum(float v) {
#pragma unroll
    for (int o = 32; o > 0; o >>= 1) v += __shfl_down(v, o, 64);
    return v;
}

__device__ __forceinline__ float dot4(float4 a, float4 b) {
    return a.x * b.x + a.y * b.y + a.z * b.z + a.w * b.w;
}

__device__ __forceinline__ float sigmoidf_(float x) {
    return 1.0f / (1.0f + expf(-x));
}

// One block per LSTM unit k (1024 blocks). Wave w computes gate row w*1024+k.
// N4E = E_in/4 (compile-time -> fully unrolled dot loops).
template <int N4E>
__global__ __launch_bounds__(256) void lstm_kernel(
    const float* __restrict__ x_base, const int* __restrict__ ids,
    const float* __restrict__ W_ih, const float* __restrict__ W_hh,
    const float* __restrict__ b_ih, const float* __restrict__ b_hh,
    const float* __restrict__ hprev, const float* __restrict__ cprev,
    float* __restrict__ h_ws, float* __restrict__ h_out, float* __restrict__ c_out,
    float* __restrict__ zero_base, int zero_count)
{
    // fused zero-init of ws atomic-accumulation regions
    if (zero_base != nullptr) {
        int idx = blockIdx.x * 256 + threadIdx.x;
        if (idx < zero_count) zero_base[idx] = 0.0f;
    }

    const float* x = (ids != nullptr) ? (x_base + (size_t)(4 * N4E) * (size_t)ids[0]) : x_base;

    const int k = blockIdx.x;          // unit [0,1024)
    const int w = threadIdx.x >> 6;    // wave 0..3 -> gate i,f,g,o
    const int lane = threadIdx.x & 63;
    const int row = w * 1024 + k;

    float acc = 0.0f;
    {
        const float4* r4 = (const float4*)(W_ih + (size_t)row * (4 * N4E));
        const float4* x4 = (const float4*)x;
#pragma unroll
        for (int j = 0; j < N4E / 64; ++j)
            acc += dot4(r4[lane + 64 * j], x4[lane + 64 * j]);
    }
    {
        const float4* r4 = (const float4*)(W_hh + (size_t)row * 1024);
        const float4* h4 = (const float4*)hprev;
#pragma unroll
        for (int j = 0; j < 4; ++j)
            acc += dot4(r4[lane + 64 * j], h4[lane + 64 * j]);
    }
    acc = wave_sum(acc);

    __shared__ float g[4];
    if (lane == 0) g[w] = acc + b_ih[row] + b_hh[row];
    __syncthreads();
    if (threadIdx.x == 0) {
        float i_ = sigmoidf_(g[0]);
        float f_ = sigmoidf_(g[1]);
        float g_ = tanhf(g[2]);
        float o_ = sigmoidf_(g[3]);
        float c_new = f_ * cprev[k] + i_ * g_;
        float h_new = o_ * tanhf(c_new);
        h_ws[k] = h_new;
        h_out[k] = h_new;
        c_out[k] = c_new;
    }
}

// v[a][c] = sum_h W_a[h][c] * q[h]  (b.q term dropped: softmax-invariant).
// Grid: 3*64 blocks; block = (a, 16-row chunk); 1 atomic per 16 rows.
__global__ __launch_bounds__(256) void attn_v_kernel(
    const float* __restrict__ W0, const float* __restrict__ W1,
    const float* __restrict__ W2, const float* __restrict__ q,
    float* __restrict__ v)
{
    const int a = blockIdx.x >> 6;
    const int chunk = blockIdx.x & 63;
    const float* W = (a == 0) ? W0 : (a == 1) ? W1 : W2;
    const int c = threadIdx.x * 4;
    float4 acc = make_float4(0.f, 0.f, 0.f, 0.f);
#pragma unroll 4
    for (int h = chunk * 16; h < chunk * 16 + 16; ++h) {
        float qh = q[h];
        float4 wv = *(const float4*)(W + (size_t)h * 1024 + c);
        acc.x += wv.x * qh; acc.y += wv.y * qh;
        acc.z += wv.z * qh; acc.w += wv.w * qh;
    }
    float* vd = v + a * 1024 + c;
    atomicAdd(vd + 0, acc.x); atomicAdd(vd + 1, acc.y);
    atomicAdd(vd + 2, acc.z); atomicAdd(vd + 3, acc.w);
}

// e[a][s] = ctx_a[s][:] . v[a][:]   (6144 wave-dots; grid 1536 x 256)
__global__ __launch_bounds__(256) void attn_e_kernel(
    const float* __restrict__ C0, const float* __restrict__ C1,
    const float* __restrict__ C2, const float* __restrict__ v,
    float* __restrict__ e)
{
    const int wid = (blockIdx.x * 256 + threadIdx.x) >> 6;
    const int lane = threadIdx.x & 63;
    const int a = wid >> 11;
    const int s = wid & 2047;
    const float* ctx = (a == 0) ? C0 : (a == 1) ? C1 : C2;
    const float4* r4 = (const float4*)(ctx + (size_t)s * 1024);
    const float4* v4 = (const float4*)(v + a * 1024);
    float acc = 0.0f;
#pragma unroll
    for (int j = 0; j < 4; ++j) acc += dot4(r4[lane + 64 * j], v4[lane + 64 * j]);
    acc = wave_sum(acc);
    if (lane == 0) e[a * 2048 + s] = acc;
}

// softmax over e[a][:] (recomputed per block; e is 8KB, L2-hot) then
// ctx_out[a][c] += sum_s p[s]*ctx[s][c] over this block's 32-row chunk.
__global__ __launch_bounds__(256) void attn_ctx_kernel(
    const float* __restrict__ C0, const float* __restrict__ C1,
    const float* __restrict__ C2, const float* __restrict__ e,
    float* __restrict__ ctx_out)
{
    const int a = blockIdx.x >> 6;
    const int chunk = blockIdx.x & 63;
    const float* ctx = (a == 0) ? C0 : (a == 1) ? C1 : C2;
    const float* ea = e + a * 2048;

    __shared__ float red[256];
    const int t = threadIdx.x;
    float m = -1e30f;
    for (int i = t; i < 2048; i += 256) m = fmaxf(m, ea[i]);
    red[t] = m; __syncthreads();
    for (int o = 128; o > 0; o >>= 1) {
        if (t < o) red[t] = fmaxf(red[t], red[t + o]);
        __syncthreads();
    }
    m = red[0]; __syncthreads();

    float ssum = 0.0f;
    for (int i = t; i < 2048; i += 256) ssum += expf(ea[i] - m);
    red[t] = ssum; __syncthreads();
    for (int o = 128; o > 0; o >>= 1) {
        if (t < o) red[t] += red[t + o];
        __syncthreads();
    }
    const float inv = 1.0f / red[0];

    const int c = t * 4;
    float4 acc = make_float4(0.f, 0.f, 0.f, 0.f);
    for (int s = chunk * 32; s < chunk * 32 + 32; ++s) {
        float wgt = expf(ea[s] - m) * inv;
        float4 cv = *(const float4*)(ctx + (size_t)s * 1024 + c);
        acc.x += wgt * cv.x; acc.y += wgt * cv.y;
        acc.z += wgt * cv.z; acc.w += wgt * cv.w;
    }
    float* od = ctx_out + a * 1024 + c;
    atomicAdd(od + 0, acc.x); atomicAdd(od + 1, acc.y);
    atomicAdd(od + 2, acc.z); atomicAdd(od + 3, acc.w);
}

// concat_out[j] = tanh(W_concat[j][:] . concat_in + b[j])  (1024 wave-dots of 4096)
__global__ __launch_bounds__(256) void concat_kernel(
    const float* __restrict__ W, const float* __restrict__ b,
    const float* __restrict__ cin, float* __restrict__ cout)
{
    const int w = threadIdx.x >> 6;
    const int lane = threadIdx.x & 63;
    const int j = blockIdx.x * 4 + w;
    const float4* r4 = (const float4*)(W + (size_t)j * 4096);
    const float4* x4 = (const float4*)cin;
    float acc = 0.0f;
#pragma unroll
    for (int jj = 0; jj < 16; ++jj) acc += dot4(r4[lane + 64 * jj], x4[lane + 64 * jj]);
    acc = wave_sum(acc);
    if (lane == 0) cout[j] = tanhf(acc + b[j]);
}

// logits[vrow] = W_out[vrow][:] . concat_out + b_out[vrow]
// One row per wave, no loop: 50257 waves -> 12565 blocks. Max MLP.
__global__ __launch_bounds__(256) void out_kernel(
    const float* __restrict__ W, const float* __restrict__ b,
    const float* __restrict__ x, float* __restrict__ out)
{
    const int vrow = (blockIdx.x * 256 + threadIdx.x) >> 6;
    const int lane = threadIdx.x & 63;
    if (vrow >= OUT_V) return;
    const float bias = (lane == 0) ? b[vrow] : 0.0f;   // issue early, hide behind row loads
    const float4* r4 = (const float4*)(W + (size_t)vrow * 1024);
    const float4* x4 = (const float4*)x;
    float acc = dot4(r4[lane], x4[lane])
              + dot4(r4[lane + 64], x4[lane + 64])
              + dot4(r4[lane + 128], x4[lane + 128])
              + dot4(r4[lane + 192], x4[lane + 192]);
    acc = wave_sum(acc);
    if (lane == 0) out[vrow] = acc + bias;
}

extern "C" void kernel_launch(void* const* d_in, const int* in_sizes, int n_in,
                              void* d_out, int out_size, void* d_ws, size_t ws_size,
                              hipStream_t stream) {
    const int*   input_ids = (const int*)  d_in[0];
    const float* h0        = (const float*)d_in[1];
    const float* c0        = (const float*)d_in[2];
    const float* lctx      = (const float*)d_in[3];
    const float* rctx      = (const float*)d_in[4];
    const float* lemma     = (const float*)d_in[5];
    const float* emb       = (const float*)d_in[6];
    const float* W_ih0     = (const float*)d_in[7];
    const float* W_hh0     = (const float*)d_in[8];
    const float* b_ih0     = (const float*)d_in[9];
    const float* b_hh0     = (const float*)d_in[10];
    const float* W_ih1     = (const float*)d_in[11];
    const float* W_hh1     = (const float*)d_in[12];
    const float* b_ih1     = (const float*)d_in[13];
    const float* b_hh1     = (const float*)d_in[14];
    const float* W_left    = (const float*)d_in[15];
    // d_in[16]/[18]/[20] attention biases: softmax-invariant, dropped
    const float* W_right   = (const float*)d_in[17];
    const float* W_lemma   = (const float*)d_in[19];
    const float* W_concat  = (const float*)d_in[21];
    const float* b_concat  = (const float*)d_in[22];
    const float* W_out     = (const float*)d_in[23];
    const float* b_out     = (const float*)d_in[24];
    (void)in_sizes; (void)n_in; (void)out_size; (void)ws_size;

    float* out = (float*)d_out;
    float* ws  = (float*)d_ws;

    float* h0_out = out + OUT_V;
    float* h1_out = out + OUT_V + 1024;
    float* c0_out = out + OUT_V + 2048;
    float* c1_out = out + OUT_V + 3072;

    // K1: LSTM layer 0 (+ zero ws[2048,8192) = ctx_out + v atomic accumulators)
    lstm_kernel<128><<<1024, 256, 0, stream>>>(
        emb, input_ids, W_ih0, W_hh0, b_ih0, b_hh0,
        h0, c0, ws + WS_H0, h0_out, c0_out,
        ws + WS_CTXOUT, 6144);

    // K2: LSTM layer 1
    lstm_kernel<256><<<1024, 256, 0, stream>>>(
        ws + WS_H0, nullptr, W_ih1, W_hh1, b_ih1, b_hh1,
        h0 + 1024, c0 + 1024, ws + WS_CONCAT_IN, h1_out, c1_out,
        nullptr, 0);

    // K3: v_a = q @ W_a
    attn_v_kernel<<<192, 256, 0, stream>>>(
        W_left, W_right, W_lemma, ws + WS_CONCAT_IN, ws + WS_V);

    // K4: e[a][s] = ctx_a[s] . v_a
    attn_e_kernel<<<1536, 256, 0, stream>>>(
        lctx, rctx, lemma, ws + WS_V, ws + WS_E);

    // K5: softmax + weighted context sum -> ctx_out region of concat_in
    attn_ctx_kernel<<<192, 256, 0, stream>>>(
        lctx, rctx, lemma, ws + WS_E, ws + WS_CTXOUT);

    // K6: concat projection + tanh
    concat_kernel<<<256, 256, 0, stream>>>(
        W_concat, b_concat, ws + WS_CONCAT_IN, ws + WS_COUT);

    // K7: vocab projection (206 MB, the roofline term) — one row per wave
    out_kernel<<<(OUT_V * 64 + 255) / 256, 256, 0, stream>>>(
        W_out, b_out, ws + WS_COUT, out);
}